// Round 14
// baseline (354.909 us; speedup 1.0000x reference)
//
#include <hip/hip_runtime.h>
#include <math.h>

#define NN   65536      // total nodes
#define NPG  4096       // nodes per graph
#define NB   16         // graphs
#define NE   524288     // real edges
#define EPG  32768      // edges per graph
#define SB   8          // sub-blocks per graph (4096 edges each)
#define NH   128        // hidden
#define FN   8          // node feat
#define FE   4          // edge feat
#define NG   16         // global feat
#define NA   10         // actions

typedef __attribute__((ext_vector_type(8))) short bf16x8;
typedef __attribute__((ext_vector_type(4))) float f32x4;
typedef __attribute__((ext_vector_type(4))) float vf4;

static __device__ __forceinline__ short bf16rne(float f) {
    unsigned u = __builtin_bit_cast(unsigned, f);
    u += 0x7FFFu + ((u >> 16) & 1u);
    return (short)(u >> 16);
}
// nontemporal float4 load (streamed read-once data: keep L2 for the xl gather set)
static __device__ __forceinline__ float4 ntload4(const float4* p) {
    vf4 v = __builtin_nontemporal_load((const vf4*)p);
    return make_float4(v.x, v.y, v.z, v.w);
}

// ---------------- fused: per-sub-block LDS histograms (128 blocks) + lin1 (rest) ----------------
// Graph g's edges are contiguous with dst in [g*NPG,(g+1)*NPG) -> LDS histogram per
// (graph, sub-block); NO global atomics anywhere in prep. subhist fully overwritten.
__global__ void hist_lin1_kernel(const int* __restrict__ ei, int* __restrict__ subhist,
                                 const float* __restrict__ x,
                                 const float* __restrict__ Wl, const float* __restrict__ Wr,
                                 float* __restrict__ xl, float* __restrict__ xr) {
    int bid = blockIdx.x;
    if (bid < NB * SB) {
        __shared__ int hh[NPG];
        int g = bid >> 3, sb = bid & 7;
        int t = threadIdx.x;
        for (int i = t; i < NPG; i += 256) hh[i] = 0;
        __syncthreads();
        const int* dstp = ei + NE + g * EPG + sb * (EPG / SB);
        for (int i = t; i < EPG / SB; i += 256)
            atomicAdd(&hh[dstp[i] - g * NPG], 1);
        __syncthreads();
        int* out = subhist + (size_t)bid * NPG;
        for (int i = t; i < NPG; i += 256) out[i] = hh[i];
    } else {
        __shared__ float row[2][FN];
        int b2 = bid - NB * SB;
        int sub = threadIdx.x >> 7;
        int k = threadIdx.x & 127;
        int n = b2 * 2 + sub;
        if (k < FN) row[sub][k] = x[n * FN + k];
        __syncthreads();
        float al = 0.f, ar = 0.f;
#pragma unroll
        for (int j = 0; j < FN; ++j) {
            float v = row[sub][j];
            al += v * Wl[j * NH + k];
            ar += v * Wr[j * NH + k];
        }
        xl[n * NH + k] = al;
        xr[n * NH + k] = ar;
    }
}

// ---------------- per-graph scan: subhist -> offs + per-sub-block cursor bases ----------------
__global__ __launch_bounds__(1024) void scan_kernel(
        const int* __restrict__ subhist, int* __restrict__ offs, int* __restrict__ cur2) {
    __shared__ int psum[1024];
    int g = blockIdx.x, t = threadIdx.x;
    int h[4][SB];
    int deg[4], loc[4];
    int run = 0;
#pragma unroll
    for (int i = 0; i < 4; ++i) {
        int nl = t * 4 + i;
        int d = 0;
#pragma unroll
        for (int sb = 0; sb < SB; ++sb) {
            int v = subhist[((size_t)(g * SB + sb)) * NPG + nl];
            h[i][sb] = v;
            d += v;
        }
        deg[i] = d;
        loc[i] = run;
        run += d;
    }
    psum[t] = run;
    __syncthreads();
    for (int s = 1; s < 1024; s <<= 1) {
        int add = (t >= s) ? psum[t - s] : 0;
        __syncthreads();
        psum[t] += add;
        __syncthreads();
    }
    int prefix = (t == 0) ? 0 : psum[t - 1];
    int ebase = g * EPG;
#pragma unroll
    for (int i = 0; i < 4; ++i) {
        int nl = t * 4 + i;
        int off = ebase + prefix + loc[i];
        offs[g * NPG + nl] = off;
        int running = off;
#pragma unroll
        for (int sb = 0; sb < SB; ++sb) {
            cur2[((size_t)(g * SB + sb)) * NPG + nl] = running;
            running += h[i][sb];
        }
    }
    if (g == NB - 1 && t == 0) offs[NN] = NE;
    (void)deg;
}

// ---------------- CSR fill: LDS cursors per (graph, sub-block) — zero global atomics ----------------
__global__ __launch_bounds__(1024) void csr_fill_kernel(
        const int* __restrict__ ei, const int* __restrict__ cur2, int2* __restrict__ csr) {
    __shared__ int cur[NPG];
    int bid = blockIdx.x;
    int g = bid >> 3, sb = bid & 7;
    int t = threadIdx.x;
    const int* base = cur2 + (size_t)bid * NPG;
    for (int i = t; i < NPG; i += 1024) cur[i] = base[i];
    __syncthreads();
    int e0 = g * EPG + sb * (EPG / SB);
#pragma unroll
    for (int i = 0; i < (EPG / SB) / 1024; ++i) {
        int e = e0 + i * 1024 + t;
        int dst = ei[NE + e];
        int src = ei[e];
        int pos = atomicAdd(&cur[dst - g * NPG], 1);
        csr[pos] = make_int2(src, e);
    }
}

// ---------------- GATv2 gather: one 32-lane group per node (measured-best r11 config) ----------------
// DO NOT restructure: contiguous CSR + depth-2 idx / depth-1 data prefetch + __expf
// + runtime flags is the measured optimum (60us); 5 structural variants all regressed.
// Only change vs r13: nontemporal loads for streamed read-once arrays (xr, ea, lattr).
__global__ __launch_bounds__(256) void gat_gather_kernel(
        const float4* __restrict__ xl, const float4* __restrict__ xr,
        const float4* __restrict__ ea,
        const int2* __restrict__ csr, const int* __restrict__ offs,
        const float* __restrict__ We, const float* __restrict__ att,
        const float* __restrict__ bias, float* __restrict__ out,
        float4* __restrict__ lattr_w, const float4* __restrict__ lattr_r,
        float4* __restrict__ gpart, int do_relu) {
    __shared__ float4 red[8][32];
    int grp = threadIdx.x >> 5;
    int lane = threadIdx.x & 31;
    int bid = blockIdx.x;
    int xcd = bid & 7, slot = bid >> 3;
    int g = xcd + ((slot >> 9) << 3);   // graphs {xcd, xcd+8}
    int blk = slot & 511;               // block within graph (512 x 8 nodes)
    int node = g * NPG + blk * 8 + grp;

    float4 xr4 = ntload4(&xr[node * 32 + lane]);
    float4 att4 = ((const float4*)att)[lane];
    const float4* We4 = (const float4*)We;
    float4 we0 = We4[lane];
    float4 we1 = We4[32 + lane];
    float4 we2 = We4[64 + lane];
    float4 we3 = We4[96 + lane];

    int beg = offs[node], end = offs[node + 1];
    float l = 0.f;
    float4 acc = make_float4(0.f, 0.f, 0.f, 0.f);
    float4 easum = make_float4(0.f, 0.f, 0.f, 0.f);
    bool have_lattr = (lattr_r != nullptr);
    if (beg < end) {
        int last = end - 1;
        int2 se0 = csr[beg];
        int p1 = (beg + 1 <= last) ? beg + 1 : last;
        int2 se1 = csr[p1];
        float4 xl0 = xl[se0.x * 32 + lane];
        float4 a0 = ntload4(&ea[se0.y]);
        for (int p = beg; p < end; ++p) {
            int p2 = (p + 2 <= last) ? p + 2 : last;
            int2 se2 = csr[p2];                       // index prefetch, depth 2
            float4 xl1 = xl[se1.x * 32 + lane];       // data prefetch, depth 1
            float4 a1 = ntload4(&ea[se1.y]);
            if (!have_lattr) {
                easum.x += a0.x; easum.y += a0.y; easum.z += a0.z; easum.w += a0.w;
            }
            float tx = xl0.x + xr4.x + a0.x * we0.x + a0.y * we1.x + a0.z * we2.x + a0.w * we3.x;
            float ty = xl0.y + xr4.y + a0.x * we0.y + a0.y * we1.y + a0.z * we2.y + a0.w * we3.y;
            float tz = xl0.z + xr4.z + a0.x * we0.z + a0.y * we1.z + a0.z * we2.z + a0.w * we3.z;
            float tw = xl0.w + xr4.w + a0.x * we0.w + a0.y * we1.w + a0.z * we2.w + a0.w * we3.w;
            tx = tx > 0.f ? tx : 0.2f * tx;
            ty = ty > 0.f ? ty : 0.2f * ty;
            tz = tz > 0.f ? tz : 0.2f * tz;
            tw = tw > 0.f ? tw : 0.2f * tw;
            float s = tx * att4.x + ty * att4.y + tz * att4.z + tw * att4.w;
#pragma unroll
            for (int o = 16; o >= 1; o >>= 1) s += __shfl_xor(s, o);   // stays in 32-group
            float w = __expf(s);
            l += w;
            acc.x += w * xl0.x;
            acc.y += w * xl0.y;
            acc.z += w * xl0.z;
            acc.w += w * xl0.w;
            se1 = se2; xl0 = xl1; a0 = a1;
        }
    }
    // self-loop: src = node, attr = mean incoming ea
    {
        float ax, ay, az, aw;
        if (have_lattr) {
            float4 la = ntload4(&lattr_r[node]);
            ax = la.x; ay = la.y; az = la.z; aw = la.w;
        } else {
            int deg = end - beg;
            float invd = 1.0f / (float)(deg > 0 ? deg : 1);
            ax = easum.x * invd; ay = easum.y * invd;
            az = easum.z * invd; aw = easum.w * invd;
            if (lane == 0) lattr_w[node] = make_float4(ax, ay, az, aw);
        }
        float4 xl4 = xl[node * 32 + lane];
        float tx = xl4.x + xr4.x + ax * we0.x + ay * we1.x + az * we2.x + aw * we3.x;
        float ty = xl4.y + xr4.y + ax * we0.y + ay * we1.y + az * we2.y + aw * we3.y;
        float tz = xl4.z + xr4.z + ax * we0.z + ay * we1.z + az * we2.z + aw * we3.z;
        float tw = xl4.w + xr4.w + ax * we0.w + ay * we1.w + az * we2.w + aw * we3.w;
        tx = tx > 0.f ? tx : 0.2f * tx;
        ty = ty > 0.f ? ty : 0.2f * ty;
        tz = tz > 0.f ? tz : 0.2f * tz;
        tw = tw > 0.f ? tw : 0.2f * tw;
        float s = tx * att4.x + ty * att4.y + tz * att4.z + tw * att4.w;
#pragma unroll
        for (int o = 16; o >= 1; o >>= 1) s += __shfl_xor(s, o);
        float w = __expf(s);
        l += w;
        acc.x += w * xl4.x;
        acc.y += w * xl4.y;
        acc.z += w * xl4.z;
        acc.w += w * xl4.w;
    }
    float inv = 1.0f / l;
    float4 b4 = ((const float4*)bias)[lane];
    float4 o4;
    o4.x = acc.x * inv + b4.x;
    o4.y = acc.y * inv + b4.y;
    o4.z = acc.z * inv + b4.z;
    o4.w = acc.w * inv + b4.w;
    if (do_relu) {
        o4.x = fmaxf(o4.x, 0.f); o4.y = fmaxf(o4.y, 0.f);
        o4.z = fmaxf(o4.z, 0.f); o4.w = fmaxf(o4.w, 0.f);
    }
    ((float4*)out)[node * 32 + lane] = o4;

    // fused mean-pool partials: sum o4 over the 8 node-groups of this block
    if (gpart != nullptr) {
        red[grp][lane] = o4;
        __syncthreads();
        if (grp < 4) {
            float4 o = red[grp + 4][lane];
            red[grp][lane] = make_float4(red[grp][lane].x + o.x, red[grp][lane].y + o.y,
                                         red[grp][lane].z + o.z, red[grp][lane].w + o.w);
        }
        __syncthreads();
        if (grp < 2) {
            float4 o = red[grp + 2][lane];
            red[grp][lane] = make_float4(red[grp][lane].x + o.x, red[grp][lane].y + o.y,
                                         red[grp][lane].z + o.z, red[grp][lane].w + o.w);
        }
        __syncthreads();
        if (grp == 0) {
            float4 a = red[0][lane], b = red[1][lane];
            gpart[(g * 512 + blk) * 32 + lane] =
                make_float4(a.x + b.x, a.y + b.y, a.z + b.z, a.w + b.w);
        }
    }
}

// ---------------- layer-2 projections: bf16 MFMA (fp32 accumulate) ----------------
__global__ __launch_bounds__(256) void lin2_mfma_kernel(
        const float* __restrict__ A, const float* __restrict__ Wl2,
        const float* __restrict__ Wr2, float* __restrict__ xl, float* __restrict__ xr) {
    __shared__ short bfrag[8 * 4 * 64 * 8];   // [ct][kg][lane][j] bf16 = 32 KB
    const float* W = blockIdx.y ? Wr2 : Wl2;
    float* C = blockIdx.y ? xr : xl;
    int t = threadIdx.x;
    {
        int k = t >> 1;
        int c0 = (t & 1) * 64;
        int kg = k >> 5, ko = k & 31;
        int laneHi = (ko >> 3) << 4, j = ko & 7;
        const float4* Wrow = (const float4*)&W[k * NH + c0];
#pragma unroll
        for (int q = 0; q < 16; ++q) {
            float4 v = Wrow[q];
            float vals[4] = {v.x, v.y, v.z, v.w};
            int col = c0 + q * 4;
#pragma unroll
            for (int i = 0; i < 4; ++i) {
                int cc = col + i;
                int ct = cc >> 4;
                int lane = laneHi | (cc & 15);
                bfrag[(((ct << 2) | kg) * 64 + lane) * 8 + j] = bf16rne(vals[i]);
            }
        }
    }
    __syncthreads();
    int wv = t >> 6, lane = t & 63;
    int row0 = blockIdx.x * 64 + wv * 16;
    int m = lane & 15, qd = lane >> 4;
    bf16x8 afrag[4];
    const float* Arow = &A[(size_t)(row0 + m) * NH + qd * 8];
#pragma unroll
    for (int kg = 0; kg < 4; ++kg) {
        float4 v0 = *(const float4*)&Arow[kg * 32];
        float4 v1 = *(const float4*)&Arow[kg * 32 + 4];
        afrag[kg][0] = bf16rne(v0.x); afrag[kg][1] = bf16rne(v0.y);
        afrag[kg][2] = bf16rne(v0.z); afrag[kg][3] = bf16rne(v0.w);
        afrag[kg][4] = bf16rne(v1.x); afrag[kg][5] = bf16rne(v1.y);
        afrag[kg][6] = bf16rne(v1.z); afrag[kg][7] = bf16rne(v1.w);
    }
    const bf16x8* bf8 = (const bf16x8*)bfrag;
#pragma unroll
    for (int ct = 0; ct < 8; ++ct) {
        f32x4 acc = {0.f, 0.f, 0.f, 0.f};
#pragma unroll
        for (int kg = 0; kg < 4; ++kg) {
            bf16x8 b = bf8[((ct << 2) | kg) * 64 + lane];
            acc = __builtin_amdgcn_mfma_f32_16x16x32_bf16(afrag[kg], b, acc, 0, 0, 0);
        }
        int col = ct * 16 + m;
#pragma unroll
        for (int r = 0; r < 4; ++r)
            C[(size_t)(row0 + qd * 4 + r) * NH + col] = acc[r];
    }
}

// ---------------- head MLP: one block per graph (sums fused-pool partials) ----------------
__global__ void head_kernel(const float* __restrict__ gpart, const float* __restrict__ h,
                            const float* __restrict__ gstate, const int* __restrict__ cpn,
                            const float* __restrict__ Wc, const float* __restrict__ bc,
                            const float* __restrict__ Wa1, const float* __restrict__ ba1,
                            const float* __restrict__ Wa2, const float* __restrict__ ba2,
                            const float* __restrict__ Wv1, const float* __restrict__ bv1,
                            const float* __restrict__ Wv2, const float* __restrict__ bv2,
                            float* __restrict__ out) {
    int b = blockIdx.x, t = threadIdx.x;
    __shared__ float comb[400];
    __shared__ float feat[256];
    __shared__ float hid[256];
    int n0 = cpn[b * 2 + 0] + b * NPG;
    int n1 = cpn[b * 2 + 1] + b * NPG;
    if (t < 128) {
        float s0 = 0.f, s1 = 0.f, s2 = 0.f, s3 = 0.f;
        const float* gp = gpart + (size_t)b * 512 * NH + t;
        for (int c = 0; c < 512; c += 4) {
            s0 += gp[(c + 0) * NH];
            s1 += gp[(c + 1) * NH];
            s2 += gp[(c + 2) * NH];
            s3 += gp[(c + 3) * NH];
        }
        comb[t] = (s0 + s1 + s2 + s3) * (1.0f / NPG);
        comb[128 + t] = h[n0 * NH + t];
    } else {
        int tt = t - 128;
        comb[256 + tt] = h[n1 * NH + tt];
        if (tt < NG) comb[384 + tt] = gstate[b * NG + tt];
    }
    __syncthreads();
    float acc = bc[t];
    for (int j = 0; j < 400; ++j) acc += comb[j] * Wc[j * 256 + t];
    feat[t] = fmaxf(acc, 0.f);
    __syncthreads();
    if (t < 128) {
        float a2 = ba1[t];
        for (int j = 0; j < 256; ++j) a2 += feat[j] * Wa1[j * NH + t];
        hid[t] = fmaxf(a2, 0.f);
    } else {
        int tt = t - 128;
        float a2 = bv1[tt];
        for (int j = 0; j < 256; ++j) a2 += feat[j] * Wv1[j * NH + tt];
        hid[128 + tt] = fmaxf(a2, 0.f);
    }
    __syncthreads();
    if (t < NA) {
        float a2 = ba2[t];
        for (int j = 0; j < NH; ++j) a2 += hid[j] * Wa2[j * NA + t];
        out[b * 11 + t] = a2;
    } else if (t == NA) {
        float a2 = bv2[0];
        for (int j = 0; j < NH; ++j) a2 += hid[128 + j] * Wv2[j];
        out[b * 11 + 10] = a2;
    }
}

extern "C" void kernel_launch(void* const* d_in, const int* in_sizes, int n_in,
                              void* d_out, int out_size, void* d_ws, size_t ws_size,
                              hipStream_t stream) {
    const float* x      = (const float*)d_in[0];
    const int*   ei     = (const int*)d_in[1];
    const float* ea     = (const float*)d_in[2];
    const float* gstate = (const float*)d_in[3];
    const int*   cpn    = (const int*)d_in[4];
    const float* Wl1 = (const float*)d_in[5];
    const float* Wr1 = (const float*)d_in[6];
    const float* We1 = (const float*)d_in[7];
    const float* att1= (const float*)d_in[8];
    const float* b1  = (const float*)d_in[9];
    const float* Wl2 = (const float*)d_in[10];
    const float* Wr2 = (const float*)d_in[11];
    const float* We2 = (const float*)d_in[12];
    const float* att2= (const float*)d_in[13];
    const float* b2  = (const float*)d_in[14];
    const float* Wc  = (const float*)d_in[15];
    const float* bc  = (const float*)d_in[16];
    const float* Wa1 = (const float*)d_in[17];
    const float* ba1 = (const float*)d_in[18];
    const float* Wa2 = (const float*)d_in[19];
    const float* ba2 = (const float*)d_in[20];
    const float* Wv1 = (const float*)d_in[21];
    const float* bv1 = (const float*)d_in[22];
    const float* Wv2 = (const float*)d_in[23];
    const float* bv2 = (const float*)d_in[24];

    char* ws = (char*)d_ws;
    size_t o = 0;
    float* xl     = (float*)(ws + o); o += (size_t)NN * NH * 4;   // 32 MB
    float* xr     = (float*)(ws + o); o += (size_t)NN * NH * 4;   // 32 MB
    float* h      = (float*)(ws + o); o += (size_t)NN * NH * 4;   // 32 MB
    float* lattr  = (float*)(ws + o); o += (size_t)NN * 16;       // 1 MB
    float* gpart  = (float*)(ws + o); o += (size_t)NB * 512 * NH * 4;  // 4 MB
    int*   offs   = (int*)(ws + o);   o += (((size_t)(NN + 1) * 4 + 255) & ~(size_t)255);
    int*   subhist= (int*)(ws + o);   o += (size_t)NB * SB * NPG * 4;  // 2 MB
    int*   cur2   = (int*)(ws + o);   o += (size_t)NB * SB * NPG * 4;  // 2 MB
    int2*  csr    = (int2*)(ws + o);  o += (size_t)NE * 8;        // 4 MB
    (void)o; (void)ws_size; (void)in_sizes; (void)n_in; (void)out_size;

    hist_lin1_kernel<<<NB * SB + NN / 2, 256, 0, stream>>>(ei, subhist, x, Wl1, Wr1, xl, xr);
    scan_kernel<<<NB, 1024, 0, stream>>>(subhist, offs, cur2);
    csr_fill_kernel<<<NB * SB, 1024, 0, stream>>>(ei, cur2, csr);
    gat_gather_kernel<<<NN / 8, 256, 0, stream>>>((const float4*)xl, (const float4*)xr,
        (const float4*)ea, csr, offs, We1, att1, b1, h, (float4*)lattr, nullptr, nullptr, 1);
    lin2_mfma_kernel<<<dim3(NN / 64, 2), 256, 0, stream>>>(h, Wl2, Wr2, xl, xr);
    gat_gather_kernel<<<NN / 8, 256, 0, stream>>>((const float4*)xl, (const float4*)xr,
        (const float4*)ea, csr, offs, We2, att2, b2, h, nullptr, (const float4*)lattr,
        (float4*)gpart, 0);
    head_kernel<<<NB, 256, 0, stream>>>(gpart, h, gstate, cpn, Wc, bc, Wa1, ba1, Wa2, ba2,
                                        Wv1, bv1, Wv2, bv2, (float*)d_out);
}

// Round 15
// 323.219 us; speedup vs baseline: 1.0980x; 1.0980x over previous
//
#include <hip/hip_runtime.h>
#include <math.h>

#define NN   65536      // total nodes
#define NPG  4096       // nodes per graph
#define NB   16         // graphs
#define NE   524288     // real edges
#define EPG  32768      // edges per graph
#define SB   8          // sub-blocks per graph (4096 edges each)
#define NH   128        // hidden
#define FN   8          // node feat
#define FE   4          // edge feat
#define NG   16         // global feat
#define NA   10         // actions

typedef __attribute__((ext_vector_type(8))) short bf16x8;
typedef __attribute__((ext_vector_type(4))) float f32x4;

static __device__ __forceinline__ short bf16rne(float f) {
    unsigned u = __builtin_bit_cast(unsigned, f);
    u += 0x7FFFu + ((u >> 16) & 1u);
    return (short)(u >> 16);
}

// ---------------- fused: per-sub-block LDS histograms (128 blocks) + lin1 (rest) ----------------
// Graph g's edges are contiguous with dst in [g*NPG,(g+1)*NPG) -> LDS histogram per
// (graph, sub-block); NO global atomics anywhere in prep. subhist fully overwritten.
__global__ void hist_lin1_kernel(const int* __restrict__ ei, int* __restrict__ subhist,
                                 const float* __restrict__ x,
                                 const float* __restrict__ Wl, const float* __restrict__ Wr,
                                 float* __restrict__ xl, float* __restrict__ xr) {
    int bid = blockIdx.x;
    if (bid < NB * SB) {
        __shared__ int hh[NPG];
        int g = bid >> 3, sb = bid & 7;
        int t = threadIdx.x;
        for (int i = t; i < NPG; i += 256) hh[i] = 0;
        __syncthreads();
        const int* dstp = ei + NE + g * EPG + sb * (EPG / SB);
        for (int i = t; i < EPG / SB; i += 256)
            atomicAdd(&hh[dstp[i] - g * NPG], 1);
        __syncthreads();
        int* out = subhist + (size_t)bid * NPG;
        for (int i = t; i < NPG; i += 256) out[i] = hh[i];
    } else {
        __shared__ float row[2][FN];
        int b2 = bid - NB * SB;
        int sub = threadIdx.x >> 7;
        int k = threadIdx.x & 127;
        int n = b2 * 2 + sub;
        if (k < FN) row[sub][k] = x[n * FN + k];
        __syncthreads();
        float al = 0.f, ar = 0.f;
#pragma unroll
        for (int j = 0; j < FN; ++j) {
            float v = row[sub][j];
            al += v * Wl[j * NH + k];
            ar += v * Wr[j * NH + k];
        }
        xl[n * NH + k] = al;
        xr[n * NH + k] = ar;
    }
}

// ---------------- per-graph scan: subhist -> offs + per-sub-block cursor bases ----------------
__global__ __launch_bounds__(1024) void scan_kernel(
        const int* __restrict__ subhist, int* __restrict__ offs, int* __restrict__ cur2) {
    __shared__ int psum[1024];
    int g = blockIdx.x, t = threadIdx.x;
    int h[4][SB];
    int loc[4];
    int run = 0;
#pragma unroll
    for (int i = 0; i < 4; ++i) {
        int nl = t * 4 + i;
        int d = 0;
#pragma unroll
        for (int sb = 0; sb < SB; ++sb) {
            int v = subhist[((size_t)(g * SB + sb)) * NPG + nl];
            h[i][sb] = v;
            d += v;
        }
        loc[i] = run;
        run += d;
    }
    psum[t] = run;
    __syncthreads();
    for (int s = 1; s < 1024; s <<= 1) {
        int add = (t >= s) ? psum[t - s] : 0;
        __syncthreads();
        psum[t] += add;
        __syncthreads();
    }
    int prefix = (t == 0) ? 0 : psum[t - 1];
    int ebase = g * EPG;
#pragma unroll
    for (int i = 0; i < 4; ++i) {
        int nl = t * 4 + i;
        int off = ebase + prefix + loc[i];
        offs[g * NPG + nl] = off;
        int running = off;
#pragma unroll
        for (int sb = 0; sb < SB; ++sb) {
            cur2[((size_t)(g * SB + sb)) * NPG + nl] = running;
            running += h[i][sb];
        }
    }
    if (g == NB - 1 && t == 0) offs[NN] = NE;
}

// ---------------- CSR fill: LDS cursors per (graph, sub-block) — zero global atomics ----------------
__global__ __launch_bounds__(1024) void csr_fill_kernel(
        const int* __restrict__ ei, const int* __restrict__ cur2, int2* __restrict__ csr) {
    __shared__ int cur[NPG];
    int bid = blockIdx.x;
    int g = bid >> 3, sb = bid & 7;
    int t = threadIdx.x;
    const int* base = cur2 + (size_t)bid * NPG;
    for (int i = t; i < NPG; i += 1024) cur[i] = base[i];
    __syncthreads();
    int e0 = g * EPG + sb * (EPG / SB);
#pragma unroll
    for (int i = 0; i < (EPG / SB) / 1024; ++i) {
        int e = e0 + i * 1024 + t;
        int dst = ei[NE + e];
        int src = ei[e];
        int pos = atomicAdd(&cur[dst - g * NPG], 1);
        csr[pos] = make_int2(src, e);
    }
}

// ---------------- GATv2 gather: one 32-lane group per node (measured-best r11/r13 config) ----------------
// DO NOT restructure: contiguous CSR + depth-2 idx / depth-1 data prefetch + __expf
// + runtime flags + PLAIN cached loads is the measured optimum (~61us).
// Failed variants: shfl-bucket(+9), wave64/node(+54), node-major(+31), ELL(+50),
// deep pipeline(+20), nontemporal ea/xr loads(+14: 64B ea lines serve ~4 edges,
// nt bypasses that reuse -> FETCH 44->56MB).
__global__ __launch_bounds__(256) void gat_gather_kernel(
        const float4* __restrict__ xl, const float4* __restrict__ xr,
        const float4* __restrict__ ea,
        const int2* __restrict__ csr, const int* __restrict__ offs,
        const float* __restrict__ We, const float* __restrict__ att,
        const float* __restrict__ bias, float* __restrict__ out,
        float4* __restrict__ lattr_w, const float4* __restrict__ lattr_r,
        float4* __restrict__ gpart, int do_relu) {
    __shared__ float4 red[8][32];
    int grp = threadIdx.x >> 5;
    int lane = threadIdx.x & 31;
    int bid = blockIdx.x;
    int xcd = bid & 7, slot = bid >> 3;
    int g = xcd + ((slot >> 9) << 3);   // graphs {xcd, xcd+8}
    int blk = slot & 511;               // block within graph (512 x 8 nodes)
    int node = g * NPG + blk * 8 + grp;

    float4 xr4 = xr[node * 32 + lane];
    float4 att4 = ((const float4*)att)[lane];
    const float4* We4 = (const float4*)We;
    float4 we0 = We4[lane];
    float4 we1 = We4[32 + lane];
    float4 we2 = We4[64 + lane];
    float4 we3 = We4[96 + lane];

    int beg = offs[node], end = offs[node + 1];
    float l = 0.f;
    float4 acc = make_float4(0.f, 0.f, 0.f, 0.f);
    float4 easum = make_float4(0.f, 0.f, 0.f, 0.f);
    bool have_lattr = (lattr_r != nullptr);
    if (beg < end) {
        int last = end - 1;
        int2 se0 = csr[beg];
        int p1 = (beg + 1 <= last) ? beg + 1 : last;
        int2 se1 = csr[p1];
        float4 xl0 = xl[se0.x * 32 + lane];
        float4 a0 = ea[se0.y];
        for (int p = beg; p < end; ++p) {
            int p2 = (p + 2 <= last) ? p + 2 : last;
            int2 se2 = csr[p2];                       // index prefetch, depth 2
            float4 xl1 = xl[se1.x * 32 + lane];       // data prefetch, depth 1
            float4 a1 = ea[se1.y];
            if (!have_lattr) {
                easum.x += a0.x; easum.y += a0.y; easum.z += a0.z; easum.w += a0.w;
            }
            float tx = xl0.x + xr4.x + a0.x * we0.x + a0.y * we1.x + a0.z * we2.x + a0.w * we3.x;
            float ty = xl0.y + xr4.y + a0.x * we0.y + a0.y * we1.y + a0.z * we2.y + a0.w * we3.y;
            float tz = xl0.z + xr4.z + a0.x * we0.z + a0.y * we1.z + a0.z * we2.z + a0.w * we3.z;
            float tw = xl0.w + xr4.w + a0.x * we0.w + a0.y * we1.w + a0.z * we2.w + a0.w * we3.w;
            tx = tx > 0.f ? tx : 0.2f * tx;
            ty = ty > 0.f ? ty : 0.2f * ty;
            tz = tz > 0.f ? tz : 0.2f * tz;
            tw = tw > 0.f ? tw : 0.2f * tw;
            float s = tx * att4.x + ty * att4.y + tz * att4.z + tw * att4.w;
#pragma unroll
            for (int o = 16; o >= 1; o >>= 1) s += __shfl_xor(s, o);   // stays in 32-group
            float w = __expf(s);
            l += w;
            acc.x += w * xl0.x;
            acc.y += w * xl0.y;
            acc.z += w * xl0.z;
            acc.w += w * xl0.w;
            se1 = se2; xl0 = xl1; a0 = a1;
        }
    }
    // self-loop: src = node, attr = mean incoming ea
    {
        float ax, ay, az, aw;
        if (have_lattr) {
            float4 la = lattr_r[node];
            ax = la.x; ay = la.y; az = la.z; aw = la.w;
        } else {
            int deg = end - beg;
            float invd = 1.0f / (float)(deg > 0 ? deg : 1);
            ax = easum.x * invd; ay = easum.y * invd;
            az = easum.z * invd; aw = easum.w * invd;
            if (lane == 0) lattr_w[node] = make_float4(ax, ay, az, aw);
        }
        float4 xl4 = xl[node * 32 + lane];
        float tx = xl4.x + xr4.x + ax * we0.x + ay * we1.x + az * we2.x + aw * we3.x;
        float ty = xl4.y + xr4.y + ax * we0.y + ay * we1.y + az * we2.y + aw * we3.y;
        float tz = xl4.z + xr4.z + ax * we0.z + ay * we1.z + az * we2.z + aw * we3.z;
        float tw = xl4.w + xr4.w + ax * we0.w + ay * we1.w + az * we2.w + aw * we3.w;
        tx = tx > 0.f ? tx : 0.2f * tx;
        ty = ty > 0.f ? ty : 0.2f * ty;
        tz = tz > 0.f ? tz : 0.2f * tz;
        tw = tw > 0.f ? tw : 0.2f * tw;
        float s = tx * att4.x + ty * att4.y + tz * att4.z + tw * att4.w;
#pragma unroll
        for (int o = 16; o >= 1; o >>= 1) s += __shfl_xor(s, o);
        float w = __expf(s);
        l += w;
        acc.x += w * xl4.x;
        acc.y += w * xl4.y;
        acc.z += w * xl4.z;
        acc.w += w * xl4.w;
    }
    float inv = 1.0f / l;
    float4 b4 = ((const float4*)bias)[lane];
    float4 o4;
    o4.x = acc.x * inv + b4.x;
    o4.y = acc.y * inv + b4.y;
    o4.z = acc.z * inv + b4.z;
    o4.w = acc.w * inv + b4.w;
    if (do_relu) {
        o4.x = fmaxf(o4.x, 0.f); o4.y = fmaxf(o4.y, 0.f);
        o4.z = fmaxf(o4.z, 0.f); o4.w = fmaxf(o4.w, 0.f);
    }
    ((float4*)out)[node * 32 + lane] = o4;

    // fused mean-pool partials: sum o4 over the 8 node-groups of this block
    if (gpart != nullptr) {
        red[grp][lane] = o4;
        __syncthreads();
        if (grp < 4) {
            float4 o = red[grp + 4][lane];
            red[grp][lane] = make_float4(red[grp][lane].x + o.x, red[grp][lane].y + o.y,
                                         red[grp][lane].z + o.z, red[grp][lane].w + o.w);
        }
        __syncthreads();
        if (grp < 2) {
            float4 o = red[grp + 2][lane];
            red[grp][lane] = make_float4(red[grp][lane].x + o.x, red[grp][lane].y + o.y,
                                         red[grp][lane].z + o.z, red[grp][lane].w + o.w);
        }
        __syncthreads();
        if (grp == 0) {
            float4 a = red[0][lane], b = red[1][lane];
            gpart[(g * 512 + blk) * 32 + lane] =
                make_float4(a.x + b.x, a.y + b.y, a.z + b.z, a.w + b.w);
        }
    }
}

// ---------------- layer-2 projections: bf16 MFMA (fp32 accumulate) ----------------
__global__ __launch_bounds__(256) void lin2_mfma_kernel(
        const float* __restrict__ A, const float* __restrict__ Wl2,
        const float* __restrict__ Wr2, float* __restrict__ xl, float* __restrict__ xr) {
    __shared__ short bfrag[8 * 4 * 64 * 8];   // [ct][kg][lane][j] bf16 = 32 KB
    const float* W = blockIdx.y ? Wr2 : Wl2;
    float* C = blockIdx.y ? xr : xl;
    int t = threadIdx.x;
    {
        int k = t >> 1;
        int c0 = (t & 1) * 64;
        int kg = k >> 5, ko = k & 31;
        int laneHi = (ko >> 3) << 4, j = ko & 7;
        const float4* Wrow = (const float4*)&W[k * NH + c0];
#pragma unroll
        for (int q = 0; q < 16; ++q) {
            float4 v = Wrow[q];
            float vals[4] = {v.x, v.y, v.z, v.w};
            int col = c0 + q * 4;
#pragma unroll
            for (int i = 0; i < 4; ++i) {
                int cc = col + i;
                int ct = cc >> 4;
                int lane = laneHi | (cc & 15);
                bfrag[(((ct << 2) | kg) * 64 + lane) * 8 + j] = bf16rne(vals[i]);
            }
        }
    }
    __syncthreads();
    int wv = t >> 6, lane = t & 63;
    int row0 = blockIdx.x * 64 + wv * 16;
    int m = lane & 15, qd = lane >> 4;
    bf16x8 afrag[4];
    const float* Arow = &A[(size_t)(row0 + m) * NH + qd * 8];
#pragma unroll
    for (int kg = 0; kg < 4; ++kg) {
        float4 v0 = *(const float4*)&Arow[kg * 32];
        float4 v1 = *(const float4*)&Arow[kg * 32 + 4];
        afrag[kg][0] = bf16rne(v0.x); afrag[kg][1] = bf16rne(v0.y);
        afrag[kg][2] = bf16rne(v0.z); afrag[kg][3] = bf16rne(v0.w);
        afrag[kg][4] = bf16rne(v1.x); afrag[kg][5] = bf16rne(v1.y);
        afrag[kg][6] = bf16rne(v1.z); afrag[kg][7] = bf16rne(v1.w);
    }
    const bf16x8* bf8 = (const bf16x8*)bfrag;
#pragma unroll
    for (int ct = 0; ct < 8; ++ct) {
        f32x4 acc = {0.f, 0.f, 0.f, 0.f};
#pragma unroll
        for (int kg = 0; kg < 4; ++kg) {
            bf16x8 b = bf8[((ct << 2) | kg) * 64 + lane];
            acc = __builtin_amdgcn_mfma_f32_16x16x32_bf16(afrag[kg], b, acc, 0, 0, 0);
        }
        int col = ct * 16 + m;
#pragma unroll
        for (int r = 0; r < 4; ++r)
            C[(size_t)(row0 + qd * 4 + r) * NH + col] = acc[r];
    }
}

// ---------------- head MLP: one block per graph (sums fused-pool partials) ----------------
__global__ void head_kernel(const float* __restrict__ gpart, const float* __restrict__ h,
                            const float* __restrict__ gstate, const int* __restrict__ cpn,
                            const float* __restrict__ Wc, const float* __restrict__ bc,
                            const float* __restrict__ Wa1, const float* __restrict__ ba1,
                            const float* __restrict__ Wa2, const float* __restrict__ ba2,
                            const float* __restrict__ Wv1, const float* __restrict__ bv1,
                            const float* __restrict__ Wv2, const float* __restrict__ bv2,
                            float* __restrict__ out) {
    int b = blockIdx.x, t = threadIdx.x;
    __shared__ float comb[400];
    __shared__ float feat[256];
    __shared__ float hid[256];
    int n0 = cpn[b * 2 + 0] + b * NPG;
    int n1 = cpn[b * 2 + 1] + b * NPG;
    if (t < 128) {
        float s0 = 0.f, s1 = 0.f, s2 = 0.f, s3 = 0.f;
        const float* gp = gpart + (size_t)b * 512 * NH + t;
        for (int c = 0; c < 512; c += 4) {
            s0 += gp[(c + 0) * NH];
            s1 += gp[(c + 1) * NH];
            s2 += gp[(c + 2) * NH];
            s3 += gp[(c + 3) * NH];
        }
        comb[t] = (s0 + s1 + s2 + s3) * (1.0f / NPG);
        comb[128 + t] = h[n0 * NH + t];
    } else {
        int tt = t - 128;
        comb[256 + tt] = h[n1 * NH + tt];
        if (tt < NG) comb[384 + tt] = gstate[b * NG + tt];
    }
    __syncthreads();
    float acc = bc[t];
    for (int j = 0; j < 400; ++j) acc += comb[j] * Wc[j * 256 + t];
    feat[t] = fmaxf(acc, 0.f);
    __syncthreads();
    if (t < 128) {
        float a2 = ba1[t];
        for (int j = 0; j < 256; ++j) a2 += feat[j] * Wa1[j * NH + t];
        hid[t] = fmaxf(a2, 0.f);
    } else {
        int tt = t - 128;
        float a2 = bv1[tt];
        for (int j = 0; j < 256; ++j) a2 += feat[j] * Wv1[j * NH + tt];
        hid[128 + tt] = fmaxf(a2, 0.f);
    }
    __syncthreads();
    if (t < NA) {
        float a2 = ba2[t];
        for (int j = 0; j < NH; ++j) a2 += hid[j] * Wa2[j * NA + t];
        out[b * 11 + t] = a2;
    } else if (t == NA) {
        float a2 = bv2[0];
        for (int j = 0; j < NH; ++j) a2 += hid[128 + j] * Wv2[j];
        out[b * 11 + 10] = a2;
    }
}

extern "C" void kernel_launch(void* const* d_in, const int* in_sizes, int n_in,
                              void* d_out, int out_size, void* d_ws, size_t ws_size,
                              hipStream_t stream) {
    const float* x      = (const float*)d_in[0];
    const int*   ei     = (const int*)d_in[1];
    const float* ea     = (const float*)d_in[2];
    const float* gstate = (const float*)d_in[3];
    const int*   cpn    = (const int*)d_in[4];
    const float* Wl1 = (const float*)d_in[5];
    const float* Wr1 = (const float*)d_in[6];
    const float* We1 = (const float*)d_in[7];
    const float* att1= (const float*)d_in[8];
    const float* b1  = (const float*)d_in[9];
    const float* Wl2 = (const float*)d_in[10];
    const float* Wr2 = (const float*)d_in[11];
    const float* We2 = (const float*)d_in[12];
    const float* att2= (const float*)d_in[13];
    const float* b2  = (const float*)d_in[14];
    const float* Wc  = (const float*)d_in[15];
    const float* bc  = (const float*)d_in[16];
    const float* Wa1 = (const float*)d_in[17];
    const float* ba1 = (const float*)d_in[18];
    const float* Wa2 = (const float*)d_in[19];
    const float* ba2 = (const float*)d_in[20];
    const float* Wv1 = (const float*)d_in[21];
    const float* bv1 = (const float*)d_in[22];
    const float* Wv2 = (const float*)d_in[23];
    const float* bv2 = (const float*)d_in[24];

    char* ws = (char*)d_ws;
    size_t o = 0;
    float* xl     = (float*)(ws + o); o += (size_t)NN * NH * 4;   // 32 MB
    float* xr     = (float*)(ws + o); o += (size_t)NN * NH * 4;   // 32 MB
    float* h      = (float*)(ws + o); o += (size_t)NN * NH * 4;   // 32 MB
    float* lattr  = (float*)(ws + o); o += (size_t)NN * 16;       // 1 MB
    float* gpart  = (float*)(ws + o); o += (size_t)NB * 512 * NH * 4;  // 4 MB
    int*   offs   = (int*)(ws + o);   o += (((size_t)(NN + 1) * 4 + 255) & ~(size_t)255);
    int*   subhist= (int*)(ws + o);   o += (size_t)NB * SB * NPG * 4;  // 2 MB
    int*   cur2   = (int*)(ws + o);   o += (size_t)NB * SB * NPG * 4;  // 2 MB
    int2*  csr    = (int2*)(ws + o);  o += (size_t)NE * 8;        // 4 MB
    (void)o; (void)ws_size; (void)in_sizes; (void)n_in; (void)out_size;

    hist_lin1_kernel<<<NB * SB + NN / 2, 256, 0, stream>>>(ei, subhist, x, Wl1, Wr1, xl, xr);
    scan_kernel<<<NB, 1024, 0, stream>>>(subhist, offs, cur2);
    csr_fill_kernel<<<NB * SB, 1024, 0, stream>>>(ei, cur2, csr);
    gat_gather_kernel<<<NN / 8, 256, 0, stream>>>((const float4*)xl, (const float4*)xr,
        (const float4*)ea, csr, offs, We1, att1, b1, h, (float4*)lattr, nullptr, nullptr, 1);
    lin2_mfma_kernel<<<dim3(NN / 64, 2), 256, 0, stream>>>(h, Wl2, Wr2, xl, xr);
    gat_gather_kernel<<<NN / 8, 256, 0, stream>>>((const float4*)xl, (const float4*)xr,
        (const float4*)ea, csr, offs, We2, att2, b2, h, nullptr, (const float4*)lattr,
        (float4*)gpart, 0);
    head_kernel<<<NB, 256, 0, stream>>>(gpart, h, gstate, cpn, Wc, bc, Wa1, ba1, Wa2, ba2,
                                        Wv1, bv1, Wv2, bv2, (float*)d_out);
}

// Round 16
// 319.570 us; speedup vs baseline: 1.1106x; 1.0114x over previous
//
#include <hip/hip_runtime.h>
#include <math.h>

#define NN   65536      // total nodes
#define NPG  4096       // nodes per graph
#define NB   16         // graphs
#define NE   524288     // real edges
#define EPG  32768      // edges per graph
#define SB   8          // sub-blocks per graph (4096 edges each)
#define NH   128        // hidden
#define FN   8          // node feat
#define FE   4          // edge feat
#define NG   16         // global feat
#define NA   10         // actions
#define NFRAG 2048      // B fragments per matrix: 8 ct x 4 kg x 64 lanes

typedef __attribute__((ext_vector_type(8))) short bf16x8;
typedef __attribute__((ext_vector_type(4))) float f32x4;

static __device__ __forceinline__ short bf16rne(float f) {
    unsigned u = __builtin_bit_cast(unsigned, f);
    u += 0x7FFFu + ((u >> 16) & 1u);
    return (short)(u >> 16);
}

// ---------------- fused: per-sub-block LDS histograms (128 blocks) + lin1 (rest) ----------------
// Graph g's edges are contiguous with dst in [g*NPG,(g+1)*NPG) -> LDS histogram per
// (graph, sub-block); NO global atomics anywhere in prep. subhist fully overwritten.
__global__ void hist_lin1_kernel(const int* __restrict__ ei, int* __restrict__ subhist,
                                 const float* __restrict__ x,
                                 const float* __restrict__ Wl, const float* __restrict__ Wr,
                                 float* __restrict__ xl, float* __restrict__ xr) {
    int bid = blockIdx.x;
    if (bid < NB * SB) {
        __shared__ int hh[NPG];
        int g = bid >> 3, sb = bid & 7;
        int t = threadIdx.x;
        for (int i = t; i < NPG; i += 256) hh[i] = 0;
        __syncthreads();
        const int* dstp = ei + NE + g * EPG + sb * (EPG / SB);
        for (int i = t; i < EPG / SB; i += 256)
            atomicAdd(&hh[dstp[i] - g * NPG], 1);
        __syncthreads();
        int* out = subhist + (size_t)bid * NPG;
        for (int i = t; i < NPG; i += 256) out[i] = hh[i];
    } else {
        __shared__ float row[2][FN];
        int b2 = bid - NB * SB;
        int sub = threadIdx.x >> 7;
        int k = threadIdx.x & 127;
        int n = b2 * 2 + sub;
        if (k < FN) row[sub][k] = x[n * FN + k];
        __syncthreads();
        float al = 0.f, ar = 0.f;
#pragma unroll
        for (int j = 0; j < FN; ++j) {
            float v = row[sub][j];
            al += v * Wl[j * NH + k];
            ar += v * Wr[j * NH + k];
        }
        xl[n * NH + k] = al;
        xr[n * NH + k] = ar;
    }
}

// ---------------- per-graph scan (blocks < NB) + W2 bf16-fragment precompute (2 extra blocks) ----------------
// Fragment order: wbf[sel*NFRAG + (ct*4+kg)*64 + lane][j] = bf16(W[kg*32+(lane>>4)*8+j][ct*16+(lane&15)])
// Converted ONCE here instead of per-block in lin2 (2048 redundant 64KB conversions + scalar
// ds_writes were lin2's dominant cost).
__global__ __launch_bounds__(1024) void scan_kernel(
        const int* __restrict__ subhist, int* __restrict__ offs, int* __restrict__ cur2,
        const float* __restrict__ Wl2, const float* __restrict__ Wr2,
        bf16x8* __restrict__ wbf) {
    int g = blockIdx.x, t = threadIdx.x;
    if (g >= NB) {
        int sel = g - NB;
        const float* W = sel ? Wr2 : Wl2;
#pragma unroll
        for (int q = 0; q < 2; ++q) {
            int f = t * 2 + q;
            int lane = f & 63;
            int kgct = f >> 6;
            int kg = kgct & 3, ct = kgct >> 2;
            int kbase = kg * 32 + (lane >> 4) * 8;
            int c = ct * 16 + (lane & 15);
            bf16x8 v;
#pragma unroll
            for (int j = 0; j < 8; ++j)
                v[j] = bf16rne(W[(kbase + j) * NH + c]);
            wbf[sel * NFRAG + f] = v;
        }
        return;
    }
    __shared__ int psum[1024];
    int h[4][SB];
    int loc[4];
    int run = 0;
#pragma unroll
    for (int i = 0; i < 4; ++i) {
        int nl = t * 4 + i;
        int d = 0;
#pragma unroll
        for (int sb = 0; sb < SB; ++sb) {
            int v = subhist[((size_t)(g * SB + sb)) * NPG + nl];
            h[i][sb] = v;
            d += v;
        }
        loc[i] = run;
        run += d;
    }
    psum[t] = run;
    __syncthreads();
    for (int s = 1; s < 1024; s <<= 1) {
        int add = (t >= s) ? psum[t - s] : 0;
        __syncthreads();
        psum[t] += add;
        __syncthreads();
    }
    int prefix = (t == 0) ? 0 : psum[t - 1];
    int ebase = g * EPG;
#pragma unroll
    for (int i = 0; i < 4; ++i) {
        int nl = t * 4 + i;
        int off = ebase + prefix + loc[i];
        offs[g * NPG + nl] = off;
        int running = off;
#pragma unroll
        for (int sb = 0; sb < SB; ++sb) {
            cur2[((size_t)(g * SB + sb)) * NPG + nl] = running;
            running += h[i][sb];
        }
    }
    if (g == NB - 1 && t == 0) offs[NN] = NE;
}

// ---------------- CSR fill: LDS cursors per (graph, sub-block) — zero global atomics ----------------
__global__ __launch_bounds__(1024) void csr_fill_kernel(
        const int* __restrict__ ei, const int* __restrict__ cur2, int2* __restrict__ csr) {
    __shared__ int cur[NPG];
    int bid = blockIdx.x;
    int g = bid >> 3, sb = bid & 7;
    int t = threadIdx.x;
    const int* base = cur2 + (size_t)bid * NPG;
    for (int i = t; i < NPG; i += 1024) cur[i] = base[i];
    __syncthreads();
    int e0 = g * EPG + sb * (EPG / SB);
#pragma unroll
    for (int i = 0; i < (EPG / SB) / 1024; ++i) {
        int e = e0 + i * 1024 + t;
        int dst = ei[NE + e];
        int src = ei[e];
        int pos = atomicAdd(&cur[dst - g * NPG], 1);
        csr[pos] = make_int2(src, e);
    }
}

// ---------------- GATv2 gather: one 32-lane group per node (measured-best r11/r13 config) ----------------
// DO NOT restructure: contiguous CSR + depth-2 idx / depth-1 data prefetch + __expf
// + runtime flags + PLAIN cached loads is the measured optimum (~60us).
// Failed variants: shfl-bucket(+9), wave64/node(+54), node-major(+31), ELL(+50),
// deep pipeline(+20), nontemporal ea/xr loads(+14).
__global__ __launch_bounds__(256) void gat_gather_kernel(
        const float4* __restrict__ xl, const float4* __restrict__ xr,
        const float4* __restrict__ ea,
        const int2* __restrict__ csr, const int* __restrict__ offs,
        const float* __restrict__ We, const float* __restrict__ att,
        const float* __restrict__ bias, float* __restrict__ out,
        float4* __restrict__ lattr_w, const float4* __restrict__ lattr_r,
        float4* __restrict__ gpart, int do_relu) {
    __shared__ float4 red[8][32];
    int grp = threadIdx.x >> 5;
    int lane = threadIdx.x & 31;
    int bid = blockIdx.x;
    int xcd = bid & 7, slot = bid >> 3;
    int g = xcd + ((slot >> 9) << 3);   // graphs {xcd, xcd+8}
    int blk = slot & 511;               // block within graph (512 x 8 nodes)
    int node = g * NPG + blk * 8 + grp;

    float4 xr4 = xr[node * 32 + lane];
    float4 att4 = ((const float4*)att)[lane];
    const float4* We4 = (const float4*)We;
    float4 we0 = We4[lane];
    float4 we1 = We4[32 + lane];
    float4 we2 = We4[64 + lane];
    float4 we3 = We4[96 + lane];

    int beg = offs[node], end = offs[node + 1];
    float l = 0.f;
    float4 acc = make_float4(0.f, 0.f, 0.f, 0.f);
    float4 easum = make_float4(0.f, 0.f, 0.f, 0.f);
    bool have_lattr = (lattr_r != nullptr);
    if (beg < end) {
        int last = end - 1;
        int2 se0 = csr[beg];
        int p1 = (beg + 1 <= last) ? beg + 1 : last;
        int2 se1 = csr[p1];
        float4 xl0 = xl[se0.x * 32 + lane];
        float4 a0 = ea[se0.y];
        for (int p = beg; p < end; ++p) {
            int p2 = (p + 2 <= last) ? p + 2 : last;
            int2 se2 = csr[p2];                       // index prefetch, depth 2
            float4 xl1 = xl[se1.x * 32 + lane];       // data prefetch, depth 1
            float4 a1 = ea[se1.y];
            if (!have_lattr) {
                easum.x += a0.x; easum.y += a0.y; easum.z += a0.z; easum.w += a0.w;
            }
            float tx = xl0.x + xr4.x + a0.x * we0.x + a0.y * we1.x + a0.z * we2.x + a0.w * we3.x;
            float ty = xl0.y + xr4.y + a0.x * we0.y + a0.y * we1.y + a0.z * we2.y + a0.w * we3.y;
            float tz = xl0.z + xr4.z + a0.x * we0.z + a0.y * we1.z + a0.z * we2.z + a0.w * we3.z;
            float tw = xl0.w + xr4.w + a0.x * we0.w + a0.y * we1.w + a0.z * we2.w + a0.w * we3.w;
            tx = tx > 0.f ? tx : 0.2f * tx;
            ty = ty > 0.f ? ty : 0.2f * ty;
            tz = tz > 0.f ? tz : 0.2f * tz;
            tw = tw > 0.f ? tw : 0.2f * tw;
            float s = tx * att4.x + ty * att4.y + tz * att4.z + tw * att4.w;
#pragma unroll
            for (int o = 16; o >= 1; o >>= 1) s += __shfl_xor(s, o);   // stays in 32-group
            float w = __expf(s);
            l += w;
            acc.x += w * xl0.x;
            acc.y += w * xl0.y;
            acc.z += w * xl0.z;
            acc.w += w * xl0.w;
            se1 = se2; xl0 = xl1; a0 = a1;
        }
    }
    // self-loop: src = node, attr = mean incoming ea
    {
        float ax, ay, az, aw;
        if (have_lattr) {
            float4 la = lattr_r[node];
            ax = la.x; ay = la.y; az = la.z; aw = la.w;
        } else {
            int deg = end - beg;
            float invd = 1.0f / (float)(deg > 0 ? deg : 1);
            ax = easum.x * invd; ay = easum.y * invd;
            az = easum.z * invd; aw = easum.w * invd;
            if (lane == 0) lattr_w[node] = make_float4(ax, ay, az, aw);
        }
        float4 xl4 = xl[node * 32 + lane];
        float tx = xl4.x + xr4.x + ax * we0.x + ay * we1.x + az * we2.x + aw * we3.x;
        float ty = xl4.y + xr4.y + ax * we0.y + ay * we1.y + az * we2.y + aw * we3.y;
        float tz = xl4.z + xr4.z + ax * we0.z + ay * we1.z + az * we2.z + aw * we3.z;
        float tw = xl4.w + xr4.w + ax * we0.w + ay * we1.w + az * we2.w + aw * we3.w;
        tx = tx > 0.f ? tx : 0.2f * tx;
        ty = ty > 0.f ? ty : 0.2f * ty;
        tz = tz > 0.f ? tz : 0.2f * tz;
        tw = tw > 0.f ? tw : 0.2f * tw;
        float s = tx * att4.x + ty * att4.y + tz * att4.z + tw * att4.w;
#pragma unroll
        for (int o = 16; o >= 1; o >>= 1) s += __shfl_xor(s, o);
        float w = __expf(s);
        l += w;
        acc.x += w * xl4.x;
        acc.y += w * xl4.y;
        acc.z += w * xl4.z;
        acc.w += w * xl4.w;
    }
    float inv = 1.0f / l;
    float4 b4 = ((const float4*)bias)[lane];
    float4 o4;
    o4.x = acc.x * inv + b4.x;
    o4.y = acc.y * inv + b4.y;
    o4.z = acc.z * inv + b4.z;
    o4.w = acc.w * inv + b4.w;
    if (do_relu) {
        o4.x = fmaxf(o4.x, 0.f); o4.y = fmaxf(o4.y, 0.f);
        o4.z = fmaxf(o4.z, 0.f); o4.w = fmaxf(o4.w, 0.f);
    }
    ((float4*)out)[node * 32 + lane] = o4;

    // fused mean-pool partials: sum o4 over the 8 node-groups of this block
    if (gpart != nullptr) {
        red[grp][lane] = o4;
        __syncthreads();
        if (grp < 4) {
            float4 o = red[grp + 4][lane];
            red[grp][lane] = make_float4(red[grp][lane].x + o.x, red[grp][lane].y + o.y,
                                         red[grp][lane].z + o.z, red[grp][lane].w + o.w);
        }
        __syncthreads();
        if (grp < 2) {
            float4 o = red[grp + 2][lane];
            red[grp][lane] = make_float4(red[grp][lane].x + o.x, red[grp][lane].y + o.y,
                                         red[grp][lane].z + o.z, red[grp][lane].w + o.w);
        }
        __syncthreads();
        if (grp == 0) {
            float4 a = red[0][lane], b = red[1][lane];
            gpart[(g * 512 + blk) * 32 + lane] =
                make_float4(a.x + b.x, a.y + b.y, a.z + b.z, a.w + b.w);
        }
    }
}

// ---------------- layer-2 projections: bf16 MFMA, B fragments from global (no LDS) ----------------
// wbf holds both matrices in fragment order (precomputed in scan_kernel); per-wave
// B loads are lane-indexed contiguous 16B = fully coalesced, L2-resident (64KB total).
__global__ __launch_bounds__(256) void lin2_mfma_kernel(
        const float* __restrict__ A, const bf16x8* __restrict__ wbf,
        float* __restrict__ xl, float* __restrict__ xr) {
    const bf16x8* Bf = wbf + (size_t)blockIdx.y * NFRAG;
    float* C = blockIdx.y ? xr : xl;
    int t = threadIdx.x;
    int wv = t >> 6, lane = t & 63;
    int row0 = blockIdx.x * 64 + wv * 16;
    int m = lane & 15, qd = lane >> 4;
    // A fragments: lane holds A[row0+m][kg*32 + qd*8 + j], j=0..7 (m120 layout)
    bf16x8 afrag[4];
    const float* Arow = &A[(size_t)(row0 + m) * NH + qd * 8];
#pragma unroll
    for (int kg = 0; kg < 4; ++kg) {
        float4 v0 = *(const float4*)&Arow[kg * 32];
        float4 v1 = *(const float4*)&Arow[kg * 32 + 4];
        afrag[kg][0] = bf16rne(v0.x); afrag[kg][1] = bf16rne(v0.y);
        afrag[kg][2] = bf16rne(v0.z); afrag[kg][3] = bf16rne(v0.w);
        afrag[kg][4] = bf16rne(v1.x); afrag[kg][5] = bf16rne(v1.y);
        afrag[kg][6] = bf16rne(v1.z); afrag[kg][7] = bf16rne(v1.w);
    }
#pragma unroll
    for (int ct = 0; ct < 8; ++ct) {
        f32x4 acc = {0.f, 0.f, 0.f, 0.f};
#pragma unroll
        for (int kg = 0; kg < 4; ++kg) {
            bf16x8 b = Bf[((ct << 2) | kg) * 64 + lane];
            acc = __builtin_amdgcn_mfma_f32_16x16x32_bf16(afrag[kg], b, acc, 0, 0, 0);
        }
        int col = ct * 16 + m;   // C/D layout: col=lane&15, row=(lane>>4)*4+reg (m89)
#pragma unroll
        for (int r = 0; r < 4; ++r)
            C[(size_t)(row0 + qd * 4 + r) * NH + col] = acc[r];
    }
}

// ---------------- head MLP: one block per graph (sums fused-pool partials) ----------------
__global__ void head_kernel(const float* __restrict__ gpart, const float* __restrict__ h,
                            const float* __restrict__ gstate, const int* __restrict__ cpn,
                            const float* __restrict__ Wc, const float* __restrict__ bc,
                            const float* __restrict__ Wa1, const float* __restrict__ ba1,
                            const float* __restrict__ Wa2, const float* __restrict__ ba2,
                            const float* __restrict__ Wv1, const float* __restrict__ bv1,
                            const float* __restrict__ Wv2, const float* __restrict__ bv2,
                            float* __restrict__ out) {
    int b = blockIdx.x, t = threadIdx.x;
    __shared__ float comb[400];
    __shared__ float feat[256];
    __shared__ float hid[256];
    int n0 = cpn[b * 2 + 0] + b * NPG;
    int n1 = cpn[b * 2 + 1] + b * NPG;
    if (t < 128) {
        float s0 = 0.f, s1 = 0.f, s2 = 0.f, s3 = 0.f;
        const float* gp = gpart + (size_t)b * 512 * NH + t;
        for (int c = 0; c < 512; c += 4) {
            s0 += gp[(c + 0) * NH];
            s1 += gp[(c + 1) * NH];
            s2 += gp[(c + 2) * NH];
            s3 += gp[(c + 3) * NH];
        }
        comb[t] = (s0 + s1 + s2 + s3) * (1.0f / NPG);
        comb[128 + t] = h[n0 * NH + t];
    } else {
        int tt = t - 128;
        comb[256 + tt] = h[n1 * NH + tt];
        if (tt < NG) comb[384 + tt] = gstate[b * NG + tt];
    }
    __syncthreads();
    float acc = bc[t];
    for (int j = 0; j < 400; ++j) acc += comb[j] * Wc[j * 256 + t];
    feat[t] = fmaxf(acc, 0.f);
    __syncthreads();
    if (t < 128) {
        float a2 = ba1[t];
        for (int j = 0; j < 256; ++j) a2 += feat[j] * Wa1[j * NH + t];
        hid[t] = fmaxf(a2, 0.f);
    } else {
        int tt = t - 128;
        float a2 = bv1[tt];
        for (int j = 0; j < 256; ++j) a2 += feat[j] * Wv1[j * NH + tt];
        hid[128 + tt] = fmaxf(a2, 0.f);
    }
    __syncthreads();
    if (t < NA) {
        float a2 = ba2[t];
        for (int j = 0; j < NH; ++j) a2 += hid[j] * Wa2[j * NA + t];
        out[b * 11 + t] = a2;
    } else if (t == NA) {
        float a2 = bv2[0];
        for (int j = 0; j < NH; ++j) a2 += hid[128 + j] * Wv2[j];
        out[b * 11 + 10] = a2;
    }
}

extern "C" void kernel_launch(void* const* d_in, const int* in_sizes, int n_in,
                              void* d_out, int out_size, void* d_ws, size_t ws_size,
                              hipStream_t stream) {
    const float* x      = (const float*)d_in[0];
    const int*   ei     = (const int*)d_in[1];
    const float* ea     = (const float*)d_in[2];
    const float* gstate = (const float*)d_in[3];
    const int*   cpn    = (const int*)d_in[4];
    const float* Wl1 = (const float*)d_in[5];
    const float* Wr1 = (const float*)d_in[6];
    const float* We1 = (const float*)d_in[7];
    const float* att1= (const float*)d_in[8];
    const float* b1  = (const float*)d_in[9];
    const float* Wl2 = (const float*)d_in[10];
    const float* Wr2 = (const float*)d_in[11];
    const float* We2 = (const float*)d_in[12];
    const float* att2= (const float*)d_in[13];
    const float* b2  = (const float*)d_in[14];
    const float* Wc  = (const float*)d_in[15];
    const float* bc  = (const float*)d_in[16];
    const float* Wa1 = (const float*)d_in[17];
    const float* ba1 = (const float*)d_in[18];
    const float* Wa2 = (const float*)d_in[19];
    const float* ba2 = (const float*)d_in[20];
    const float* Wv1 = (const float*)d_in[21];
    const float* bv1 = (const float*)d_in[22];
    const float* Wv2 = (const float*)d_in[23];
    const float* bv2 = (const float*)d_in[24];

    char* ws = (char*)d_ws;
    size_t o = 0;
    float* xl     = (float*)(ws + o); o += (size_t)NN * NH * 4;   // 32 MB
    float* xr     = (float*)(ws + o); o += (size_t)NN * NH * 4;   // 32 MB
    float* h      = (float*)(ws + o); o += (size_t)NN * NH * 4;   // 32 MB
    float* lattr  = (float*)(ws + o); o += (size_t)NN * 16;       // 1 MB
    float* gpart  = (float*)(ws + o); o += (size_t)NB * 512 * NH * 4;  // 4 MB
    int*   offs   = (int*)(ws + o);   o += (((size_t)(NN + 1) * 4 + 255) & ~(size_t)255);
    int*   subhist= (int*)(ws + o);   o += (size_t)NB * SB * NPG * 4;  // 2 MB
    int*   cur2   = (int*)(ws + o);   o += (size_t)NB * SB * NPG * 4;  // 2 MB
    int2*  csr    = (int2*)(ws + o);  o += (size_t)NE * 8;        // 4 MB
    bf16x8* wbf   = (bf16x8*)(ws + o); o += (size_t)2 * NFRAG * 16;  // 64 KB
    (void)o; (void)ws_size; (void)in_sizes; (void)n_in; (void)out_size;

    hist_lin1_kernel<<<NB * SB + NN / 2, 256, 0, stream>>>(ei, subhist, x, Wl1, Wr1, xl, xr);
    scan_kernel<<<NB + 2, 1024, 0, stream>>>(subhist, offs, cur2, Wl2, Wr2, wbf);
    csr_fill_kernel<<<NB * SB, 1024, 0, stream>>>(ei, cur2, csr);
    gat_gather_kernel<<<NN / 8, 256, 0, stream>>>((const float4*)xl, (const float4*)xr,
        (const float4*)ea, csr, offs, We1, att1, b1, h, (float4*)lattr, nullptr, nullptr, 1);
    lin2_mfma_kernel<<<dim3(NN / 64, 2), 256, 0, stream>>>(h, wbf, xl, xr);
    gat_gather_kernel<<<NN / 8, 256, 0, stream>>>((const float4*)xl, (const float4*)xr,
        (const float4*)ea, csr, offs, We2, att2, b2, h, nullptr, (const float4*)lattr,
        (float4*)gpart, 0);
    head_kernel<<<NB, 256, 0, stream>>>(gpart, h, gstate, cpn, Wc, bc, Wa1, ba1, Wa2, ba2,
                                        Wv1, bv1, Wv2, bv2, (float*)d_out);
}

// Round 17
// 315.075 us; speedup vs baseline: 1.1264x; 1.0143x over previous
//
#include <hip/hip_runtime.h>
#include <math.h>

#define NN   65536      // total nodes
#define NPG  4096       // nodes per graph
#define NB   16         // graphs
#define NE   524288     // real edges
#define EPG  32768      // edges per graph
#define SB   8          // sub-blocks per graph (4096 edges each)
#define NH   128        // hidden
#define FN   8          // node feat
#define FE   4          // edge feat
#define NG   16         // global feat
#define NA   10         // actions
#define NFRAG 2048      // B fragments per matrix: 8 ct x 4 kg x 64 lanes

typedef __attribute__((ext_vector_type(8))) short bf16x8;
typedef __attribute__((ext_vector_type(4))) float f32x4;

static __device__ __forceinline__ short bf16rne(float f) {
    unsigned u = __builtin_bit_cast(unsigned, f);
    u += 0x7FFFu + ((u >> 16) & 1u);
    return (short)(u >> 16);
}

// ---------------- fused: per-sub-block LDS histograms (128 blocks) + lin1 (rest) ----------------
__global__ void hist_lin1_kernel(const int* __restrict__ ei, int* __restrict__ subhist,
                                 const float* __restrict__ x,
                                 const float* __restrict__ Wl, const float* __restrict__ Wr,
                                 float* __restrict__ xl, float* __restrict__ xr) {
    int bid = blockIdx.x;
    if (bid < NB * SB) {
        __shared__ int hh[NPG];
        int g = bid >> 3, sb = bid & 7;
        int t = threadIdx.x;
        for (int i = t; i < NPG; i += 256) hh[i] = 0;
        __syncthreads();
        const int* dstp = ei + NE + g * EPG + sb * (EPG / SB);
        for (int i = t; i < EPG / SB; i += 256)
            atomicAdd(&hh[dstp[i] - g * NPG], 1);
        __syncthreads();
        int* out = subhist + (size_t)bid * NPG;
        for (int i = t; i < NPG; i += 256) out[i] = hh[i];
    } else {
        __shared__ float row[2][FN];
        int b2 = bid - NB * SB;
        int sub = threadIdx.x >> 7;
        int k = threadIdx.x & 127;
        int n = b2 * 2 + sub;
        if (k < FN) row[sub][k] = x[n * FN + k];
        __syncthreads();
        float al = 0.f, ar = 0.f;
#pragma unroll
        for (int j = 0; j < FN; ++j) {
            float v = row[sub][j];
            al += v * Wl[j * NH + k];
            ar += v * Wr[j * NH + k];
        }
        xl[n * NH + k] = al;
        xr[n * NH + k] = ar;
    }
}

// ---------------- per-graph scan (blocks < NB) + W2 bf16-fragment precompute (2 extra blocks) ----------------
__global__ __launch_bounds__(1024) void scan_kernel(
        const int* __restrict__ subhist, int* __restrict__ offs, int* __restrict__ cur2,
        const float* __restrict__ Wl2, const float* __restrict__ Wr2,
        bf16x8* __restrict__ wbf) {
    int g = blockIdx.x, t = threadIdx.x;
    if (g >= NB) {
        int sel = g - NB;
        const float* W = sel ? Wr2 : Wl2;
#pragma unroll
        for (int q = 0; q < 2; ++q) {
            int f = t * 2 + q;
            int lane = f & 63;
            int kgct = f >> 6;
            int kg = kgct & 3, ct = kgct >> 2;
            int kbase = kg * 32 + (lane >> 4) * 8;
            int c = ct * 16 + (lane & 15);
            bf16x8 v;
#pragma unroll
            for (int j = 0; j < 8; ++j)
                v[j] = bf16rne(W[(kbase + j) * NH + c]);
            wbf[sel * NFRAG + f] = v;
        }
        return;
    }
    __shared__ int psum[1024];
    int h[4][SB];
    int loc[4];
    int run = 0;
#pragma unroll
    for (int i = 0; i < 4; ++i) {
        int nl = t * 4 + i;
        int d = 0;
#pragma unroll
        for (int sb = 0; sb < SB; ++sb) {
            int v = subhist[((size_t)(g * SB + sb)) * NPG + nl];
            h[i][sb] = v;
            d += v;
        }
        loc[i] = run;
        run += d;
    }
    psum[t] = run;
    __syncthreads();
    for (int s = 1; s < 1024; s <<= 1) {
        int add = (t >= s) ? psum[t - s] : 0;
        __syncthreads();
        psum[t] += add;
        __syncthreads();
    }
    int prefix = (t == 0) ? 0 : psum[t - 1];
    int ebase = g * EPG;
#pragma unroll
    for (int i = 0; i < 4; ++i) {
        int nl = t * 4 + i;
        int off = ebase + prefix + loc[i];
        offs[g * NPG + nl] = off;
        int running = off;
#pragma unroll
        for (int sb = 0; sb < SB; ++sb) {
            cur2[((size_t)(g * SB + sb)) * NPG + nl] = running;
            running += h[i][sb];
        }
    }
    if (g == NB - 1 && t == 0) offs[NN] = NE;
}

// ---------------- CSR fill: LDS cursors per (graph, sub-block) — zero global atomics ----------------
__global__ __launch_bounds__(1024) void csr_fill_kernel(
        const int* __restrict__ ei, const int* __restrict__ cur2, int2* __restrict__ csr) {
    __shared__ int cur[NPG];
    int bid = blockIdx.x;
    int g = bid >> 3, sb = bid & 7;
    int t = threadIdx.x;
    const int* base = cur2 + (size_t)bid * NPG;
    for (int i = t; i < NPG; i += 1024) cur[i] = base[i];
    __syncthreads();
    int e0 = g * EPG + sb * (EPG / SB);
#pragma unroll
    for (int i = 0; i < (EPG / SB) / 1024; ++i) {
        int e = e0 + i * 1024 + t;
        int dst = ei[NE + e];
        int src = ei[e];
        int pos = atomicAdd(&cur[dst - g * NPG], 1);
        csr[pos] = make_int2(src, e);
    }
}

// ---------------- GATv2 gather: one 32-lane group per node (measured-best r11/r13 config) ----------------
// DO NOT restructure the main loop: contiguous CSR + depth-2 idx / depth-1 data
// prefetch + __expf + runtime flags + PLAIN cached loads is the measured optimum
// (~60us). Failed variants: shfl-bucket(+9), wave64/node(+54), node-major(+31),
// ELL(+50), deep pipeline(+20), nontemporal loads(+14).
// Epilogue only (r17): MODE-1 writes h directly as bf16 MFMA A-fragments (hbf_out):
// lane's o4 = 4 contiguous j's of fragment (kg=lane>>3, qd=(lane&7)>>1, j0=4(lane&1));
// identical numerics to lin2's former per-block bf16rne, halves h traffic.
__global__ __launch_bounds__(256) void gat_gather_kernel(
        const float4* __restrict__ xl, const float4* __restrict__ xr,
        const float4* __restrict__ ea,
        const int2* __restrict__ csr, const int* __restrict__ offs,
        const float* __restrict__ We, const float* __restrict__ att,
        const float* __restrict__ bias, float* __restrict__ out,
        unsigned short* __restrict__ hbf_out,
        float4* __restrict__ lattr_w, const float4* __restrict__ lattr_r,
        float4* __restrict__ gpart, int do_relu) {
    __shared__ float4 red[8][32];
    int grp = threadIdx.x >> 5;
    int lane = threadIdx.x & 31;
    int bid = blockIdx.x;
    int xcd = bid & 7, slot = bid >> 3;
    int g = xcd + ((slot >> 9) << 3);   // graphs {xcd, xcd+8}
    int blk = slot & 511;               // block within graph (512 x 8 nodes)
    int node = g * NPG + blk * 8 + grp;

    float4 xr4 = xr[node * 32 + lane];
    float4 att4 = ((const float4*)att)[lane];
    const float4* We4 = (const float4*)We;
    float4 we0 = We4[lane];
    float4 we1 = We4[32 + lane];
    float4 we2 = We4[64 + lane];
    float4 we3 = We4[96 + lane];

    int beg = offs[node], end = offs[node + 1];
    float l = 0.f;
    float4 acc = make_float4(0.f, 0.f, 0.f, 0.f);
    float4 easum = make_float4(0.f, 0.f, 0.f, 0.f);
    bool have_lattr = (lattr_r != nullptr);
    if (beg < end) {
        int last = end - 1;
        int2 se0 = csr[beg];
        int p1 = (beg + 1 <= last) ? beg + 1 : last;
        int2 se1 = csr[p1];
        float4 xl0 = xl[se0.x * 32 + lane];
        float4 a0 = ea[se0.y];
        for (int p = beg; p < end; ++p) {
            int p2 = (p + 2 <= last) ? p + 2 : last;
            int2 se2 = csr[p2];                       // index prefetch, depth 2
            float4 xl1 = xl[se1.x * 32 + lane];       // data prefetch, depth 1
            float4 a1 = ea[se1.y];
            if (!have_lattr) {
                easum.x += a0.x; easum.y += a0.y; easum.z += a0.z; easum.w += a0.w;
            }
            float tx = xl0.x + xr4.x + a0.x * we0.x + a0.y * we1.x + a0.z * we2.x + a0.w * we3.x;
            float ty = xl0.y + xr4.y + a0.x * we0.y + a0.y * we1.y + a0.z * we2.y + a0.w * we3.y;
            float tz = xl0.z + xr4.z + a0.x * we0.z + a0.y * we1.z + a0.z * we2.z + a0.w * we3.z;
            float tw = xl0.w + xr4.w + a0.x * we0.w + a0.y * we1.w + a0.z * we2.w + a0.w * we3.w;
            tx = tx > 0.f ? tx : 0.2f * tx;
            ty = ty > 0.f ? ty : 0.2f * ty;
            tz = tz > 0.f ? tz : 0.2f * tz;
            tw = tw > 0.f ? tw : 0.2f * tw;
            float s = tx * att4.x + ty * att4.y + tz * att4.z + tw * att4.w;
#pragma unroll
            for (int o = 16; o >= 1; o >>= 1) s += __shfl_xor(s, o);   // stays in 32-group
            float w = __expf(s);
            l += w;
            acc.x += w * xl0.x;
            acc.y += w * xl0.y;
            acc.z += w * xl0.z;
            acc.w += w * xl0.w;
            se1 = se2; xl0 = xl1; a0 = a1;
        }
    }
    // self-loop: src = node, attr = mean incoming ea
    {
        float ax, ay, az, aw;
        if (have_lattr) {
            float4 la = lattr_r[node];
            ax = la.x; ay = la.y; az = la.z; aw = la.w;
        } else {
            int deg = end - beg;
            float invd = 1.0f / (float)(deg > 0 ? deg : 1);
            ax = easum.x * invd; ay = easum.y * invd;
            az = easum.z * invd; aw = easum.w * invd;
            if (lane == 0) lattr_w[node] = make_float4(ax, ay, az, aw);
        }
        float4 xl4 = xl[node * 32 + lane];
        float tx = xl4.x + xr4.x + ax * we0.x + ay * we1.x + az * we2.x + aw * we3.x;
        float ty = xl4.y + xr4.y + ax * we0.y + ay * we1.y + az * we2.y + aw * we3.y;
        float tz = xl4.z + xr4.z + ax * we0.z + ay * we1.z + az * we2.z + aw * we3.z;
        float tw = xl4.w + xr4.w + ax * we0.w + ay * we1.w + az * we2.w + aw * we3.w;
        tx = tx > 0.f ? tx : 0.2f * tx;
        ty = ty > 0.f ? ty : 0.2f * ty;
        tz = tz > 0.f ? tz : 0.2f * tz;
        tw = tw > 0.f ? tw : 0.2f * tw;
        float s = tx * att4.x + ty * att4.y + tz * att4.z + tw * att4.w;
#pragma unroll
        for (int o = 16; o >= 1; o >>= 1) s += __shfl_xor(s, o);
        float w = __expf(s);
        l += w;
        acc.x += w * xl4.x;
        acc.y += w * xl4.y;
        acc.z += w * xl4.z;
        acc.w += w * xl4.w;
    }
    float inv = 1.0f / l;
    float4 b4 = ((const float4*)bias)[lane];
    float4 o4;
    o4.x = acc.x * inv + b4.x;
    o4.y = acc.y * inv + b4.y;
    o4.z = acc.z * inv + b4.z;
    o4.w = acc.w * inv + b4.w;
    if (do_relu) {
        o4.x = fmaxf(o4.x, 0.f); o4.y = fmaxf(o4.y, 0.f);
        o4.z = fmaxf(o4.z, 0.f); o4.w = fmaxf(o4.w, 0.f);
    }
    if (hbf_out != nullptr) {
        // h as bf16 A-fragments: element (m=node&15, k=4*lane+i), rt=node>>4
        int rt = node >> 4, m = node & 15;
        int kg = lane >> 3, qd = (lane & 7) >> 1, j0 = (lane & 1) * 4;
        ushort4 v;
        v.x = (unsigned short)bf16rne(o4.x);
        v.y = (unsigned short)bf16rne(o4.y);
        v.z = (unsigned short)bf16rne(o4.z);
        v.w = (unsigned short)bf16rne(o4.w);
        *(ushort4*)&hbf_out[(size_t)(((rt * 4 + kg) * 64 + qd * 16 + m)) * 8 + j0] = v;
    } else {
        ((float4*)out)[node * 32 + lane] = o4;
    }

    // fused mean-pool partials: sum o4 over the 8 node-groups of this block
    if (gpart != nullptr) {
        red[grp][lane] = o4;
        __syncthreads();
        if (grp < 4) {
            float4 o = red[grp + 4][lane];
            red[grp][lane] = make_float4(red[grp][lane].x + o.x, red[grp][lane].y + o.y,
                                         red[grp][lane].z + o.z, red[grp][lane].w + o.w);
        }
        __syncthreads();
        if (grp < 2) {
            float4 o = red[grp + 2][lane];
            red[grp][lane] = make_float4(red[grp][lane].x + o.x, red[grp][lane].y + o.y,
                                         red[grp][lane].z + o.z, red[grp][lane].w + o.w);
        }
        __syncthreads();
        if (grp == 0) {
            float4 a = red[0][lane], b = red[1][lane];
            gpart[(g * 512 + blk) * 32 + lane] =
                make_float4(a.x + b.x, a.y + b.y, a.z + b.z, a.w + b.w);
        }
    }
}

// ---------------- layer-2 projections: bf16 MFMA, A and B fragments straight from global ----------------
// A (h) already in fragment order from gat1: lane-indexed contiguous 16B loads, zero
// conversion. B (wbf) precomputed in scan_kernel, L2-resident.
__global__ __launch_bounds__(256) void lin2_mfma_kernel(
        const bf16x8* __restrict__ hbf, const bf16x8* __restrict__ wbf,
        float* __restrict__ xl, float* __restrict__ xr) {
    const bf16x8* Bf = wbf + (size_t)blockIdx.y * NFRAG;
    float* C = blockIdx.y ? xr : xl;
    int t = threadIdx.x;
    int wv = t >> 6, lane = t & 63;
    int rt = blockIdx.x * 4 + wv;      // 16-row tile
    int row0 = rt * 16;
    int m = lane & 15, qd = lane >> 4;
    bf16x8 afrag[4];
#pragma unroll
    for (int kg = 0; kg < 4; ++kg)
        afrag[kg] = hbf[(size_t)(rt * 4 + kg) * 64 + lane];
#pragma unroll
    for (int ct = 0; ct < 8; ++ct) {
        f32x4 acc = {0.f, 0.f, 0.f, 0.f};
#pragma unroll
        for (int kg = 0; kg < 4; ++kg) {
            bf16x8 b = Bf[((ct << 2) | kg) * 64 + lane];
            acc = __builtin_amdgcn_mfma_f32_16x16x32_bf16(afrag[kg], b, acc, 0, 0, 0);
        }
        int col = ct * 16 + m;   // C/D layout: col=lane&15, row=(lane>>4)*4+reg (m89)
#pragma unroll
        for (int r = 0; r < 4; ++r)
            C[(size_t)(row0 + qd * 4 + r) * NH + col] = acc[r];
    }
}

// ---------------- head MLP: one block per graph (sums fused-pool partials) ----------------
__global__ void head_kernel(const float* __restrict__ gpart, const float* __restrict__ h,
                            const float* __restrict__ gstate, const int* __restrict__ cpn,
                            const float* __restrict__ Wc, const float* __restrict__ bc,
                            const float* __restrict__ Wa1, const float* __restrict__ ba1,
                            const float* __restrict__ Wa2, const float* __restrict__ ba2,
                            const float* __restrict__ Wv1, const float* __restrict__ bv1,
                            const float* __restrict__ Wv2, const float* __restrict__ bv2,
                            float* __restrict__ out) {
    int b = blockIdx.x, t = threadIdx.x;
    __shared__ float comb[400];
    __shared__ float feat[256];
    __shared__ float hid[256];
    int n0 = cpn[b * 2 + 0] + b * NPG;
    int n1 = cpn[b * 2 + 1] + b * NPG;
    if (t < 128) {
        float s0 = 0.f, s1 = 0.f, s2 = 0.f, s3 = 0.f;
        const float* gp = gpart + (size_t)b * 512 * NH + t;
        for (int c = 0; c < 512; c += 4) {
            s0 += gp[(c + 0) * NH];
            s1 += gp[(c + 1) * NH];
            s2 += gp[(c + 2) * NH];
            s3 += gp[(c + 3) * NH];
        }
        comb[t] = (s0 + s1 + s2 + s3) * (1.0f / NPG);
        comb[128 + t] = h[n0 * NH + t];
    } else {
        int tt = t - 128;
        comb[256 + tt] = h[n1 * NH + tt];
        if (tt < NG) comb[384 + tt] = gstate[b * NG + tt];
    }
    __syncthreads();
    float acc = bc[t];
    for (int j = 0; j < 400; ++j) acc += comb[j] * Wc[j * 256 + t];
    feat[t] = fmaxf(acc, 0.f);
    __syncthreads();
    if (t < 128) {
        float a2 = ba1[t];
        for (int j = 0; j < 256; ++j) a2 += feat[j] * Wa1[j * NH + t];
        hid[t] = fmaxf(a2, 0.f);
    } else {
        int tt = t - 128;
        float a2 = bv1[tt];
        for (int j = 0; j < 256; ++j) a2 += feat[j] * Wv1[j * NH + tt];
        hid[128 + tt] = fmaxf(a2, 0.f);
    }
    __syncthreads();
    if (t < NA) {
        float a2 = ba2[t];
        for (int j = 0; j < NH; ++j) a2 += hid[j] * Wa2[j * NA + t];
        out[b * 11 + t] = a2;
    } else if (t == NA) {
        float a2 = bv2[0];
        for (int j = 0; j < NH; ++j) a2 += hid[128 + j] * Wv2[j];
        out[b * 11 + 10] = a2;
    }
}

extern "C" void kernel_launch(void* const* d_in, const int* in_sizes, int n_in,
                              void* d_out, int out_size, void* d_ws, size_t ws_size,
                              hipStream_t stream) {
    const float* x      = (const float*)d_in[0];
    const int*   ei     = (const int*)d_in[1];
    const float* ea     = (const float*)d_in[2];
    const float* gstate = (const float*)d_in[3];
    const int*   cpn    = (const int*)d_in[4];
    const float* Wl1 = (const float*)d_in[5];
    const float* Wr1 = (const float*)d_in[6];
    const float* We1 = (const float*)d_in[7];
    const float* att1= (const float*)d_in[8];
    const float* b1  = (const float*)d_in[9];
    const float* Wl2 = (const float*)d_in[10];
    const float* Wr2 = (const float*)d_in[11];
    const float* We2 = (const float*)d_in[12];
    const float* att2= (const float*)d_in[13];
    const float* b2  = (const float*)d_in[14];
    const float* Wc  = (const float*)d_in[15];
    const float* bc  = (const float*)d_in[16];
    const float* Wa1 = (const float*)d_in[17];
    const float* ba1 = (const float*)d_in[18];
    const float* Wa2 = (const float*)d_in[19];
    const float* ba2 = (const float*)d_in[20];
    const float* Wv1 = (const float*)d_in[21];
    const float* bv1 = (const float*)d_in[22];
    const float* Wv2 = (const float*)d_in[23];
    const float* bv2 = (const float*)d_in[24];

    char* ws = (char*)d_ws;
    size_t o = 0;
    float* xl     = (float*)(ws + o); o += (size_t)NN * NH * 4;   // 32 MB
    float* xr     = (float*)(ws + o); o += (size_t)NN * NH * 4;   // 32 MB
    float* h      = (float*)(ws + o); o += (size_t)NN * NH * 4;   // 32 MB (h2 only)
    unsigned short* hbf = (unsigned short*)(ws + o); o += (size_t)NN * NH * 2;  // 16 MB (h1 bf16 frags)
    float* lattr  = (float*)(ws + o); o += (size_t)NN * 16;       // 1 MB
    float* gpart  = (float*)(ws + o); o += (size_t)NB * 512 * NH * 4;  // 4 MB
    int*   offs   = (int*)(ws + o);   o += (((size_t)(NN + 1) * 4 + 255) & ~(size_t)255);
    int*   subhist= (int*)(ws + o);   o += (size_t)NB * SB * NPG * 4;  // 2 MB
    int*   cur2   = (int*)(ws + o);   o += (size_t)NB * SB * NPG * 4;  // 2 MB
    int2*  csr    = (int2*)(ws + o);  o += (size_t)NE * 8;        // 4 MB
    bf16x8* wbf   = (bf16x8*)(ws + o); o += (size_t)2 * NFRAG * 16;  // 64 KB
    (void)o; (void)ws_size; (void)in_sizes; (void)n_in; (void)out_size;

    hist_lin1_kernel<<<NB * SB + NN / 2, 256, 0, stream>>>(ei, subhist, x, Wl1, Wr1, xl, xr);
    scan_kernel<<<NB + 2, 1024, 0, stream>>>(subhist, offs, cur2, Wl2, Wr2, wbf);
    csr_fill_kernel<<<NB * SB, 1024, 0, stream>>>(ei, cur2, csr);
    gat_gather_kernel<<<NN / 8, 256, 0, stream>>>((const float4*)xl, (const float4*)xr,
        (const float4*)ea, csr, offs, We1, att1, b1, nullptr, hbf,
        (float4*)lattr, nullptr, nullptr, 1);
    lin2_mfma_kernel<<<dim3(NN / 64, 2), 256, 0, stream>>>((const bf16x8*)hbf, wbf, xl, xr);
    gat_gather_kernel<<<NN / 8, 256, 0, stream>>>((const float4*)xl, (const float4*)xr,
        (const float4*)ea, csr, offs, We2, att2, b2, h, nullptr,
        nullptr, (const float4*)lattr, (float4*)gpart, 0);
    head_kernel<<<NB, 256, 0, stream>>>(gpart, h, gstate, cpn, Wc, bc, Wa1, ba1, Wa2, ba2,
                                        Wv1, bv1, Wv2, bv2, (float*)d_out);
}